// Round 1
// baseline (523.343 us; speedup 1.0000x reference)
//
#include <hip/hip_runtime.h>

// ---------------------------------------------------------------------------
// 3-layer GCN + linear head.  N=50000 nodes, E=800000 edges, D=128.
// Strategy: build CSR (dst-sorted adjacency) once per launch via counting
// sort, then alternate [fp32 tiled GEMM] and [wave-per-node CSR aggregation].
// ---------------------------------------------------------------------------

#define D 128

// ---- degree/count init ----------------------------------------------------
__global__ __launch_bounds__(256) void k_init(float* deg, int* cnt, int N) {
    int i = blockIdx.x * 256 + threadIdx.x;
    if (i < N) { deg[i] = 1.0f; cnt[i] = 0; }   // self-loop weight 1.0
}

// ---- pass 1: weighted degree + edge count per dst -------------------------
__global__ __launch_bounds__(256) void k_edge_pass1(const int* __restrict__ dst,
                                                    const float* __restrict__ w,
                                                    float* deg, int* cnt, int E) {
    int e = blockIdx.x * 256 + threadIdx.x;
    if (e < E) {
        int d = dst[e];
        atomicAdd(&deg[d], w[e]);
        atomicAdd(&cnt[d], 1);
    }
}

// ---- dinv = rsqrt(deg) in place (deg >= 1 always due to self loop) --------
__global__ __launch_bounds__(256) void k_dinv(float* deg, int N) {
    int i = blockIdx.x * 256 + threadIdx.x;
    if (i < N) deg[i] = rsqrtf(deg[i]);
}

// ---- block-wide exclusive scan helper (256 threads) -----------------------
__device__ inline int block_exscan_256(int v) {
    int tid = threadIdx.x;
    int lane = tid & 63, wv = tid >> 6;
    int incl = v;
#pragma unroll
    for (int d = 1; d < 64; d <<= 1) {
        int n = __shfl_up(incl, d, 64);
        if (lane >= d) incl += n;
    }
    __shared__ int wsum[4];
    if (lane == 63) wsum[wv] = incl;
    __syncthreads();
    int woff = 0;
#pragma unroll
    for (int j = 0; j < 4; j++) woff += (j < wv) ? wsum[j] : 0;
    return woff + incl - v;
}

// ---- scan stage a: per-block sums ----------------------------------------
__global__ __launch_bounds__(256) void k_scan_a(const int* __restrict__ cnt,
                                                int* bsum, int N) {
    int i = blockIdx.x * 256 + threadIdx.x;
    int v = (i < N) ? cnt[i] : 0;
#pragma unroll
    for (int d = 32; d; d >>= 1) v += __shfl_down(v, d, 64);
    __shared__ int ws4[4];
    int lane = threadIdx.x & 63, wv = threadIdx.x >> 6;
    if (lane == 0) ws4[wv] = v;
    __syncthreads();
    if (threadIdx.x == 0) bsum[blockIdx.x] = ws4[0] + ws4[1] + ws4[2] + ws4[3];
}

// ---- scan stage b: exclusive scan of block sums (nb <= 256) ---------------
__global__ __launch_bounds__(256) void k_scan_b(const int* __restrict__ bsum,
                                                int* boff, int nb) {
    int tid = threadIdx.x;
    int v = (tid < nb) ? bsum[tid] : 0;
    int ex = block_exscan_256(v);
    if (tid < nb) boff[tid] = ex;
}

// ---- scan stage c: row_ptr = global exclusive prefix; zero cnt ------------
__global__ __launch_bounds__(256) void k_scan_c(const int* __restrict__ cnt,
                                                const int* __restrict__ boff,
                                                int* rp, int* cnt_out, int N, int E) {
    int i = blockIdx.x * 256 + threadIdx.x;
    int v = (i < N) ? cnt[i] : 0;
    int ex = block_exscan_256(v);
    if (i < N) {
        rp[i] = boff[blockIdx.x] + ex;
        cnt_out[i] = 0;
    }
    if (i == 0) rp[N] = E;
}

// ---- CSR fill: col + premultiplied norm value -----------------------------
__global__ __launch_bounds__(256) void k_fill(const int* __restrict__ ei,
                                              const float* __restrict__ w,
                                              const float* __restrict__ dinv,
                                              const int* __restrict__ rp,
                                              int* cnt, int* col, float* val, int E) {
    int e = blockIdx.x * 256 + threadIdx.x;
    if (e < E) {
        int s = ei[e];
        int d = ei[E + e];
        int p = rp[d] + atomicAdd(&cnt[d], 1);
        col[p] = s;
        val[p] = dinv[s] * w[e] * dinv[d];
    }
}

// ---- fp32 tiled GEMM: C[N,128] = A[N,128] @ W[128,128] (+bias) ------------
// 64 rows per block, 256 threads, each thread: 4 rows x 8 cols register tile.
__global__ __launch_bounds__(256) void k_gemm(const float* __restrict__ A,
                                              const float* __restrict__ W,
                                              const float* __restrict__ bias,
                                              float* __restrict__ C, int N) {
    __shared__ float At[32][68];   // transposed A tile [k][row], pad->16B-aligned rows
    __shared__ float Wt[32][128];  // W tile [k][col]
    int tid = threadIdx.x;
    int row0 = blockIdx.x * 64;
    int tx = tid & 15, ty = tid >> 4;   // tx: col group (8 cols), ty: row group (4 rows)

    float acc[4][8];
#pragma unroll
    for (int r = 0; r < 4; r++)
#pragma unroll
        for (int c = 0; c < 8; c++) acc[r][c] = 0.0f;

    for (int k0 = 0; k0 < 128; k0 += 32) {
        // stage W tile: 32x128 floats
#pragma unroll
        for (int j = 0; j < 4; j++) {
            int e = tid * 4 + j * 1024;
            int r = e >> 7, c = e & 127;
            *(float4*)&Wt[r][c] = *(const float4*)&W[(k0 + r) * 128 + c];
        }
        // stage A tile transposed: 64 rows x 32 k
#pragma unroll
        for (int j = 0; j < 2; j++) {
            int e = tid * 4 + j * 1024;
            int r = e >> 5, c = e & 31;
            int grow = row0 + r;
            float4 v = make_float4(0.f, 0.f, 0.f, 0.f);
            if (grow < N) v = *(const float4*)&A[grow * 128 + k0 + c];
            At[c + 0][r] = v.x; At[c + 1][r] = v.y;
            At[c + 2][r] = v.z; At[c + 3][r] = v.w;
        }
        __syncthreads();
#pragma unroll
        for (int kk = 0; kk < 32; kk++) {
            float4 a  = *(const float4*)&At[kk][ty * 4];
            float4 w0 = *(const float4*)&Wt[kk][tx * 8];
            float4 w1 = *(const float4*)&Wt[kk][tx * 8 + 4];
            float av[4] = {a.x, a.y, a.z, a.w};
            float wv[8] = {w0.x, w0.y, w0.z, w0.w, w1.x, w1.y, w1.z, w1.w};
#pragma unroll
            for (int r = 0; r < 4; r++)
#pragma unroll
                for (int c = 0; c < 8; c++)
                    acc[r][c] = fmaf(av[r], wv[c], acc[r][c]);
        }
        __syncthreads();
    }

    float bv[8] = {0, 0, 0, 0, 0, 0, 0, 0};
    if (bias) {
        float4 b0 = *(const float4*)&bias[tx * 8];
        float4 b1 = *(const float4*)&bias[tx * 8 + 4];
        bv[0] = b0.x; bv[1] = b0.y; bv[2] = b0.z; bv[3] = b0.w;
        bv[4] = b1.x; bv[5] = b1.y; bv[6] = b1.z; bv[7] = b1.w;
    }
#pragma unroll
    for (int r = 0; r < 4; r++) {
        int row = row0 + ty * 4 + r;
        if (row < N) {
            float4 o0 = make_float4(acc[r][0] + bv[0], acc[r][1] + bv[1],
                                    acc[r][2] + bv[2], acc[r][3] + bv[3]);
            float4 o1 = make_float4(acc[r][4] + bv[4], acc[r][5] + bv[5],
                                    acc[r][6] + bv[6], acc[r][7] + bv[7]);
            *(float4*)&C[row * 128 + tx * 8] = o0;
            *(float4*)&C[row * 128 + tx * 8 + 4] = o1;
        }
    }
}

// ---- aggregation: one wave per node, lane l handles features {2l, 2l+1} ---
__global__ __launch_bounds__(256) void k_agg(const float* __restrict__ h,
                                             const int* __restrict__ rp,
                                             const int* __restrict__ col,
                                             const float* __restrict__ val,
                                             const float* __restrict__ dinv,
                                             const float* __restrict__ bias,
                                             float* __restrict__ out,
                                             int N, int relu) {
    int wave = blockIdx.x * 4 + (threadIdx.x >> 6);
    int lane = threadIdx.x & 63;
    if (wave >= N) return;
    int i = wave;

    float di = dinv[i];
    float self = di * di;
    float2 b  = *(const float2*)&bias[lane * 2];
    float2 hi = *(const float2*)&h[(size_t)i * D + lane * 2];
    float2 acc;
    acc.x = b.x + self * hi.x;
    acc.y = b.y + self * hi.y;

    int e0 = rp[i], e1 = rp[i + 1];
    int e = e0;
    // unroll-by-2 with prefetch of col/val to overlap gather latency
    for (; e + 1 < e1; e += 2) {
        int c0 = col[e];     float v0 = val[e];
        int c1 = col[e + 1]; float v1 = val[e + 1];
        float2 h0 = *(const float2*)&h[(size_t)c0 * D + lane * 2];
        float2 h1 = *(const float2*)&h[(size_t)c1 * D + lane * 2];
        acc.x = fmaf(v0, h0.x, acc.x); acc.y = fmaf(v0, h0.y, acc.y);
        acc.x = fmaf(v1, h1.x, acc.x); acc.y = fmaf(v1, h1.y, acc.y);
    }
    if (e < e1) {
        int c0 = col[e]; float v0 = val[e];
        float2 h0 = *(const float2*)&h[(size_t)c0 * D + lane * 2];
        acc.x = fmaf(v0, h0.x, acc.x); acc.y = fmaf(v0, h0.y, acc.y);
    }
    if (relu) { acc.x = fmaxf(acc.x, 0.f); acc.y = fmaxf(acc.y, 0.f); }
    *(float2*)&out[(size_t)i * D + lane * 2] = acc;
}

// ---------------------------------------------------------------------------
extern "C" void kernel_launch(void* const* d_in, const int* in_sizes, int n_in,
                              void* d_out, int out_size, void* d_ws, size_t ws_size,
                              hipStream_t stream) {
    const float* x  = (const float*)d_in[0];
    const int*   ei = (const int*)d_in[1];     // [2,E] row-major: src then dst
    const float* ew = (const float*)d_in[2];
    const float* W1 = (const float*)d_in[3];
    const float* b1 = (const float*)d_in[4];
    const float* W2 = (const float*)d_in[5];
    const float* b2 = (const float*)d_in[6];
    const float* W3 = (const float*)d_in[7];
    const float* b3 = (const float*)d_in[8];
    const float* Wl = (const float*)d_in[9];
    const float* bl = (const float*)d_in[10];

    int N = in_sizes[0] / D;    // 50000
    int E = in_sizes[2];        // 800000

    char* ws = (char*)d_ws;
    size_t off = 0;
    auto alloc = [&](size_t bytes) {
        void* p = ws + off;
        off = (off + bytes + 255) & ~(size_t)255;
        return p;
    };
    float* deg  = (float*)alloc((size_t)N * 4);          // becomes dinv in place
    int*   cnt  = (int*)  alloc((size_t)N * 4);
    int*   bsum = (int*)  alloc(1024);
    int*   boff = (int*)  alloc(1024);
    int*   rp   = (int*)  alloc((size_t)(N + 1) * 4);
    int*   col  = (int*)  alloc((size_t)E * 4);
    float* val  = (float*)alloc((size_t)E * 4);
    float* bufB = (float*)alloc((size_t)N * D * 4);
    float* bufA = (float*)d_out;                          // ping-pong with d_out

    int nbN = (N + 255) / 256;      // 196 (must be <= 256 for k_scan_b)
    int nbE = (E + 255) / 256;

    k_init<<<nbN, 256, 0, stream>>>(deg, cnt, N);
    k_edge_pass1<<<nbE, 256, 0, stream>>>(ei + E, ew, deg, cnt, E);
    k_dinv<<<nbN, 256, 0, stream>>>(deg, N);
    k_scan_a<<<nbN, 256, 0, stream>>>(cnt, bsum, N);
    k_scan_b<<<1, 256, 0, stream>>>(bsum, boff, nbN);
    k_scan_c<<<nbN, 256, 0, stream>>>(cnt, boff, rp, cnt, N, E);
    k_fill<<<nbE, 256, 0, stream>>>(ei, ew, deg, rp, cnt, col, val, E);

    int gg = (N + 63) / 64;     // GEMM blocks
    int ga = (N + 3) / 4;       // agg blocks (4 waves each)

    k_gemm<<<gg, 256, 0, stream>>>(x,    W1, nullptr, bufA, N);
    k_agg <<<ga, 256, 0, stream>>>(bufA, rp, col, val, deg, b1, bufB, N, 1);
    k_gemm<<<gg, 256, 0, stream>>>(bufB, W2, nullptr, bufA, N);
    k_agg <<<ga, 256, 0, stream>>>(bufA, rp, col, val, deg, b2, bufB, N, 1);
    k_gemm<<<gg, 256, 0, stream>>>(bufB, W3, nullptr, bufA, N);
    k_agg <<<ga, 256, 0, stream>>>(bufA, rp, col, val, deg, b3, bufB, N, 0);
    k_gemm<<<gg, 256, 0, stream>>>(bufB, Wl, bl, (float*)d_out, N);
}

// Round 2
// 448.200 us; speedup vs baseline: 1.1677x; 1.1677x over previous
//
#include <hip/hip_runtime.h>

// ---------------------------------------------------------------------------
// 3-layer GCN + linear head.  N=50000 nodes, E=800000 edges, D=128.
// CSR build via counting sort with a SINGLE u64 atomic per edge
// (count<<32 | fixed-point weight), then [fp32 tiled GEMM] x4 and
// [wave-per-node CSR aggregation] x3.
// ---------------------------------------------------------------------------

#define D 128
#define FXS 16777216.0f   // 2^24 fixed-point scale for edge-weight sums

// ---- init packed degree/count (self-loop weight 1.0 handled in k_dinv) ----
__global__ __launch_bounds__(256) void k_init(unsigned long long* packed, int N) {
    int i = blockIdx.x * 256 + threadIdx.x;
    if (i < N) packed[i] = 0ull;
}

// ---- pass 1: one u64 atomic per edge; old count -> per-edge CSR slot ------
__global__ __launch_bounds__(256) void k_edge_pass1(const int* __restrict__ dst,
                                                    const float* __restrict__ w,
                                                    unsigned long long* packed,
                                                    int* __restrict__ loc, int E) {
    int e = blockIdx.x * 256 + threadIdx.x;
    if (e < E) {
        int d = dst[e];
        unsigned long long add =
            (1ull << 32) | (unsigned long long)__float2uint_rn(w[e] * FXS);
        unsigned long long old = atomicAdd(&packed[d], add);
        loc[e] = (int)(old >> 32);
    }
}

// ---- dinv = rsqrt(1 + fxsum); also extract integer count for the scan -----
__global__ __launch_bounds__(256) void k_dinv(const unsigned long long* __restrict__ packed,
                                              float* dinv, int* cnt, int N) {
    int i = blockIdx.x * 256 + threadIdx.x;
    if (i < N) {
        unsigned long long p = packed[i];
        float deg = 1.0f + (float)(unsigned int)(p & 0xffffffffull) * (1.0f / FXS);
        dinv[i] = rsqrtf(deg);
        cnt[i] = (int)(p >> 32);
    }
}

// ---- block-wide exclusive scan helper (256 threads) -----------------------
__device__ inline int block_exscan_256(int v) {
    int tid = threadIdx.x;
    int lane = tid & 63, wv = tid >> 6;
    int incl = v;
#pragma unroll
    for (int d = 1; d < 64; d <<= 1) {
        int n = __shfl_up(incl, d, 64);
        if (lane >= d) incl += n;
    }
    __shared__ int wsum[4];
    if (lane == 63) wsum[wv] = incl;
    __syncthreads();
    int woff = 0;
#pragma unroll
    for (int j = 0; j < 4; j++) woff += (j < wv) ? wsum[j] : 0;
    return woff + incl - v;
}

// ---- scan stage a: per-block sums ----------------------------------------
__global__ __launch_bounds__(256) void k_scan_a(const int* __restrict__ cnt,
                                                int* bsum, int N) {
    int i = blockIdx.x * 256 + threadIdx.x;
    int v = (i < N) ? cnt[i] : 0;
#pragma unroll
    for (int d = 32; d; d >>= 1) v += __shfl_down(v, d, 64);
    __shared__ int ws4[4];
    int lane = threadIdx.x & 63, wv = threadIdx.x >> 6;
    if (lane == 0) ws4[wv] = v;
    __syncthreads();
    if (threadIdx.x == 0) bsum[blockIdx.x] = ws4[0] + ws4[1] + ws4[2] + ws4[3];
}

// ---- scan stage b: exclusive scan of block sums (nb <= 256) ---------------
__global__ __launch_bounds__(256) void k_scan_b(const int* __restrict__ bsum,
                                                int* boff, int nb) {
    int tid = threadIdx.x;
    int v = (tid < nb) ? bsum[tid] : 0;
    int ex = block_exscan_256(v);
    if (tid < nb) boff[tid] = ex;
}

// ---- scan stage c: row_ptr = global exclusive prefix ----------------------
__global__ __launch_bounds__(256) void k_scan_c(const int* __restrict__ cnt,
                                                const int* __restrict__ boff,
                                                int* rp, int N, int E) {
    int i = blockIdx.x * 256 + threadIdx.x;
    int v = (i < N) ? cnt[i] : 0;
    int ex = block_exscan_256(v);
    if (i < N) rp[i] = boff[blockIdx.x] + ex;
    if (i == 0) rp[N] = E;
}

// ---- CSR fill: NO atomics (slot precomputed in pass1) ---------------------
__global__ __launch_bounds__(256) void k_fill(const int* __restrict__ ei,
                                              const float* __restrict__ w,
                                              const float* __restrict__ dinv,
                                              const int* __restrict__ rp,
                                              const int* __restrict__ loc,
                                              int* col, float* val, int E) {
    int e = blockIdx.x * 256 + threadIdx.x;
    if (e < E) {
        int s = ei[e];
        int d = ei[E + e];
        int p = rp[d] + loc[e];
        col[p] = s;
        val[p] = dinv[s] * w[e] * dinv[d];
    }
}

// ---- fp32 tiled GEMM: C[N,128] = A[N,128] @ W[128,128] (+bias) ------------
// 64 rows per block, 256 threads, each thread: 4 rows x 8 cols register tile.
// Output cols for thread tx: {tx*4..tx*4+3} and {64+tx*4..64+tx*4+3}
// (stride-4 mapping -> 2-way LDS access on Wt, free; stride-8 was 4-way).
__global__ __launch_bounds__(256) void k_gemm(const float* __restrict__ A,
                                              const float* __restrict__ W,
                                              const float* __restrict__ bias,
                                              float* __restrict__ C, int N) {
    __shared__ float At[32][68];   // transposed A tile [k][row]
    __shared__ float Wt[32][128];  // W tile [k][col]
    int tid = threadIdx.x;
    int row0 = blockIdx.x * 64;
    int tx = tid & 15, ty = tid >> 4;

    float acc[4][8];
#pragma unroll
    for (int r = 0; r < 4; r++)
#pragma unroll
        for (int c = 0; c < 8; c++) acc[r][c] = 0.0f;

    for (int k0 = 0; k0 < 128; k0 += 32) {
#pragma unroll
        for (int j = 0; j < 4; j++) {
            int e = tid * 4 + j * 1024;
            int r = e >> 7, c = e & 127;
            *(float4*)&Wt[r][c] = *(const float4*)&W[(k0 + r) * 128 + c];
        }
#pragma unroll
        for (int j = 0; j < 2; j++) {
            int e = tid * 4 + j * 1024;
            int r = e >> 5, c = e & 31;
            int grow = row0 + r;
            float4 v = make_float4(0.f, 0.f, 0.f, 0.f);
            if (grow < N) v = *(const float4*)&A[grow * 128 + k0 + c];
            At[c + 0][r] = v.x; At[c + 1][r] = v.y;
            At[c + 2][r] = v.z; At[c + 3][r] = v.w;
        }
        __syncthreads();
#pragma unroll
        for (int kk = 0; kk < 32; kk++) {
            float4 a  = *(const float4*)&At[kk][ty * 4];
            float4 w0 = *(const float4*)&Wt[kk][tx * 4];
            float4 w1 = *(const float4*)&Wt[kk][64 + tx * 4];
            float av[4] = {a.x, a.y, a.z, a.w};
            float wv[8] = {w0.x, w0.y, w0.z, w0.w, w1.x, w1.y, w1.z, w1.w};
#pragma unroll
            for (int r = 0; r < 4; r++)
#pragma unroll
                for (int c = 0; c < 8; c++)
                    acc[r][c] = fmaf(av[r], wv[c], acc[r][c]);
        }
        __syncthreads();
    }

    float bv[8] = {0, 0, 0, 0, 0, 0, 0, 0};
    if (bias) {
        float4 b0 = *(const float4*)&bias[tx * 4];
        float4 b1 = *(const float4*)&bias[64 + tx * 4];
        bv[0] = b0.x; bv[1] = b0.y; bv[2] = b0.z; bv[3] = b0.w;
        bv[4] = b1.x; bv[5] = b1.y; bv[6] = b1.z; bv[7] = b1.w;
    }
#pragma unroll
    for (int r = 0; r < 4; r++) {
        int row = row0 + ty * 4 + r;
        if (row < N) {
            float4 o0 = make_float4(acc[r][0] + bv[0], acc[r][1] + bv[1],
                                    acc[r][2] + bv[2], acc[r][3] + bv[3]);
            float4 o1 = make_float4(acc[r][4] + bv[4], acc[r][5] + bv[5],
                                    acc[r][6] + bv[6], acc[r][7] + bv[7]);
            *(float4*)&C[row * 128 + tx * 4] = o0;
            *(float4*)&C[row * 128 + 64 + tx * 4] = o1;
        }
    }
}

// ---- aggregation: one wave per node; half-wave per edge, float4 per lane --
// lanes 0-31 process even-slot edges, lanes 32-63 odd-slot edges; each lane
// covers 4 features (sl*4..sl*4+3). Cross-half shuffle reduction at the end.
__global__ __launch_bounds__(256) void k_agg(const float* __restrict__ h,
                                             const int* __restrict__ rp,
                                             const int* __restrict__ col,
                                             const float* __restrict__ val,
                                             const float* __restrict__ dinv,
                                             const float* __restrict__ bias,
                                             float* __restrict__ out,
                                             int N, int relu) {
    int wave = blockIdx.x * 4 + (threadIdx.x >> 6);
    if (wave >= N) return;
    int lane = threadIdx.x & 63;
    int half = lane >> 5;
    int sl = lane & 31;
    int i = wave;

    float4 acc = make_float4(0.f, 0.f, 0.f, 0.f);
    int e0 = rp[i], e1 = rp[i + 1];
    int e = e0;
    // 4 edges in flight per wave (2 halves x unroll 2)
    for (; e + 4 <= e1; e += 4) {
        int   cA = col[e + half];     float vA = val[e + half];
        int   cB = col[e + 2 + half]; float vB = val[e + 2 + half];
        float4 hA = *(const float4*)&h[(size_t)cA * D + sl * 4];
        float4 hB = *(const float4*)&h[(size_t)cB * D + sl * 4];
        acc.x = fmaf(vA, hA.x, acc.x); acc.y = fmaf(vA, hA.y, acc.y);
        acc.z = fmaf(vA, hA.z, acc.z); acc.w = fmaf(vA, hA.w, acc.w);
        acc.x = fmaf(vB, hB.x, acc.x); acc.y = fmaf(vB, hB.y, acc.y);
        acc.z = fmaf(vB, hB.z, acc.z); acc.w = fmaf(vB, hB.w, acc.w);
    }
    if (e + 2 <= e1) {
        int cA = col[e + half]; float vA = val[e + half];
        float4 hA = *(const float4*)&h[(size_t)cA * D + sl * 4];
        acc.x = fmaf(vA, hA.x, acc.x); acc.y = fmaf(vA, hA.y, acc.y);
        acc.z = fmaf(vA, hA.z, acc.z); acc.w = fmaf(vA, hA.w, acc.w);
        e += 2;
    }
    if (e < e1 && half == 0) {
        int cA = col[e]; float vA = val[e];
        float4 hA = *(const float4*)&h[(size_t)cA * D + sl * 4];
        acc.x = fmaf(vA, hA.x, acc.x); acc.y = fmaf(vA, hA.y, acc.y);
        acc.z = fmaf(vA, hA.z, acc.z); acc.w = fmaf(vA, hA.w, acc.w);
    }
    // combine the two half-wave partial sums (lane l <-> lane l^32)
    acc.x += __shfl_xor(acc.x, 32, 64);
    acc.y += __shfl_xor(acc.y, 32, 64);
    acc.z += __shfl_xor(acc.z, 32, 64);
    acc.w += __shfl_xor(acc.w, 32, 64);

    if (half == 0) {
        float di = dinv[i];
        float self = di * di;
        float4 hi = *(const float4*)&h[(size_t)i * D + sl * 4];
        float4 b  = *(const float4*)&bias[sl * 4];
        float4 o;
        o.x = acc.x + b.x + self * hi.x;
        o.y = acc.y + b.y + self * hi.y;
        o.z = acc.z + b.z + self * hi.z;
        o.w = acc.w + b.w + self * hi.w;
        if (relu) {
            o.x = fmaxf(o.x, 0.f); o.y = fmaxf(o.y, 0.f);
            o.z = fmaxf(o.z, 0.f); o.w = fmaxf(o.w, 0.f);
        }
        *(float4*)&out[(size_t)i * D + sl * 4] = o;
    }
}

// ---------------------------------------------------------------------------
extern "C" void kernel_launch(void* const* d_in, const int* in_sizes, int n_in,
                              void* d_out, int out_size, void* d_ws, size_t ws_size,
                              hipStream_t stream) {
    const float* x  = (const float*)d_in[0];
    const int*   ei = (const int*)d_in[1];     // [2,E]: src row then dst row
    const float* ew = (const float*)d_in[2];
    const float* W1 = (const float*)d_in[3];
    const float* b1 = (const float*)d_in[4];
    const float* W2 = (const float*)d_in[5];
    const float* b2 = (const float*)d_in[6];
    const float* W3 = (const float*)d_in[7];
    const float* b3 = (const float*)d_in[8];
    const float* Wl = (const float*)d_in[9];
    const float* bl = (const float*)d_in[10];

    int N = in_sizes[0] / D;    // 50000
    int E = in_sizes[2];        // 800000

    char* ws = (char*)d_ws;
    size_t off = 0;
    auto alloc = [&](size_t bytes) {
        void* p = ws + off;
        off = (off + bytes + 255) & ~(size_t)255;
        return p;
    };
    unsigned long long* packed = (unsigned long long*)alloc((size_t)N * 8);
    float* dinv = (float*)alloc((size_t)N * 4);
    int*   cnt  = (int*)  alloc((size_t)N * 4);
    int*   bsum = (int*)  alloc(1024);
    int*   boff = (int*)  alloc(1024);
    int*   rp   = (int*)  alloc((size_t)(N + 1) * 4);
    int*   loc  = (int*)  alloc((size_t)E * 4);
    int*   col  = (int*)  alloc((size_t)E * 4);
    float* val  = (float*)alloc((size_t)E * 4);
    float* bufB = (float*)alloc((size_t)N * D * 4);
    float* bufA = (float*)d_out;                          // ping-pong with d_out

    int nbN = (N + 255) / 256;      // 196 (<= 256 for k_scan_b)
    int nbE = (E + 255) / 256;

    k_init<<<nbN, 256, 0, stream>>>(packed, N);
    k_edge_pass1<<<nbE, 256, 0, stream>>>(ei + E, ew, packed, loc, E);
    k_dinv<<<nbN, 256, 0, stream>>>(packed, dinv, cnt, N);
    k_scan_a<<<nbN, 256, 0, stream>>>(cnt, bsum, N);
    k_scan_b<<<1, 256, 0, stream>>>(bsum, boff, nbN);
    k_scan_c<<<nbN, 256, 0, stream>>>(cnt, boff, rp, N, E);
    k_fill<<<nbE, 256, 0, stream>>>(ei, ew, dinv, rp, loc, col, val, E);

    int gg = (N + 63) / 64;     // GEMM blocks
    int ga = (N + 3) / 4;       // agg blocks (4 waves each)

    k_gemm<<<gg, 256, 0, stream>>>(x,    W1, nullptr, bufA, N);
    k_agg <<<ga, 256, 0, stream>>>(bufA, rp, col, val, dinv, b1, bufB, N, 1);
    k_gemm<<<gg, 256, 0, stream>>>(bufB, W2, nullptr, bufA, N);
    k_agg <<<ga, 256, 0, stream>>>(bufA, rp, col, val, dinv, b2, bufB, N, 1);
    k_gemm<<<gg, 256, 0, stream>>>(bufB, W3, nullptr, bufA, N);
    k_agg <<<ga, 256, 0, stream>>>(bufA, rp, col, val, dinv, b3, bufB, N, 0);
    k_gemm<<<gg, 256, 0, stream>>>(bufB, Wl, bl, (float*)d_out, N);
}